// Round 9
// baseline (365.382 us; speedup 1.0000x reference)
//
#include <hip/hip_runtime.h>

typedef __bf16 bf16x8 __attribute__((ext_vector_type(8)));
typedef float  f32x4  __attribute__((ext_vector_type(4)));

// o tile per 32-pixel block: [8 heads][96 rows][32 cols] bf16 = 49152 B.
// Within-head col order is PERMUTED: col k' holds d = (k'&1)*16 + (k'>>1).
// w_out is pre-permuted identically along k, so out_proj is unchanged.
#define OTILE 49152

static __device__ __forceinline__ unsigned short f2b(float f) {
  __bf16 h = (__bf16)f;
  return __builtin_bit_cast(unsigned short, h);
}

// ---- repack weights into MFMA-fragment-linear bf16 tiles ----
// w_in  -> [48 ntile][8 ks][64 lane][8]   (natural k)
// w_out -> [16 ntile][8 h8][64 lane][8]   (k permuted: pos kp holds d=(kp&1)*16+(kp>>1))
// w_conv-> [16 ntile][24 ks][64 lane][8]  (natural k)
__global__ void repack_weights(const float* __restrict__ w_in,
                               const float* __restrict__ w_out,
                               const float* __restrict__ w_conv,
                               __bf16* __restrict__ ws) {
  int g = blockIdx.x * 256 + threadIdx.x;   // granule id, 0..57343
  __bf16* dst = ws + (size_t)g * 8;
  if (g < 24576) {                          // w_in
    int nt = g >> 9, rem = g & 511;
    int ks = rem >> 6, lane = rem & 63, l15 = lane & 15, l4 = lane >> 4;
    const float* src = w_in + (size_t)(nt * 16 + l15) * 256 + ks * 32 + l4 * 8;
    float4 a = *(const float4*)src;
    float4 b = *(const float4*)(src + 4);
    dst[0]=(__bf16)a.x; dst[1]=(__bf16)a.y; dst[2]=(__bf16)a.z; dst[3]=(__bf16)a.w;
    dst[4]=(__bf16)b.x; dst[5]=(__bf16)b.y; dst[6]=(__bf16)b.z; dst[7]=(__bf16)b.w;
  } else if (g < 32768) {                   // w_out (permuted k)
    int g2 = g - 24576;
    int nt = g2 >> 9, rem = g2 & 511;
    int h8 = rem >> 6, lane = rem & 63, l15 = lane & 15, l4 = lane >> 4;
    const float* srow = w_out + (size_t)(nt * 16 + l15) * 256 + h8 * 32;
#pragma unroll
    for (int k = 0; k < 8; ++k) {
      int kp = l4 * 8 + k;
      dst[k] = (__bf16)srow[(kp & 1) * 16 + (kp >> 1)];
    }
  } else {                                  // w_conv
    int g3 = g - 32768;
    int nt = g3 / 1536, rem = g3 - nt * 1536;
    int ks = rem >> 6, lane = rem & 63, l15 = lane & 15, l4 = lane >> 4;
    const float* src = w_conv + (size_t)(nt * 16 + l15) * 768 + ks * 32 + l4 * 8;
    float4 a = *(const float4*)src;
    float4 b = *(const float4*)(src + 4);
    dst[0]=(__bf16)a.x; dst[1]=(__bf16)a.y; dst[2]=(__bf16)a.z; dst[3]=(__bf16)a.w;
    dst[4]=(__bf16)b.x; dst[5]=(__bf16)b.y; dst[6]=(__bf16)b.z; dst[7]=(__bf16)b.w;
  }
}

// ================= K1: stage x, QKV GEMM, attention; o -> global (sector-aligned) =========
__global__ __launch_bounds__(256, 3) void k1_qkv_attn(
    const float* __restrict__ cort,
    const float* __restrict__ subc,
    const float* __restrict__ vent,
    const __bf16* __restrict__ wpack,     // frag-packed w_in
    const float* __restrict__ b_in,
    char* __restrict__ o_ws) {
  __shared__ char smem[49152];   // x [96][256] bf16 swz: off=(m*512+2c)^((m&7)<<4)
  const int tid  = threadIdx.x;
  const int lane = tid & 63;
  const int wv   = tid >> 6;
  const int l15  = lane & 15;
  const int l4   = lane >> 4;
  const int blk  = blockIdx.x;
  const int img  = blk >> 7;
  const int pixbase = (blk & 127) << 5;
  const size_t base = (size_t)img * (256 * 4096) + pixbase;

  // stage x -> LDS bf16 swz (128B coalesced reads)
#pragma unroll
  for (int si = 0; si < 3; ++si) {
    const float* rp = (si == 0) ? cort : (si == 1) ? subc : vent;
    rp += base;
#pragma unroll
    for (int t = 0; t < 16; ++t) {
      int idx = t * 256 + tid;
      int p   = idx & 31;
      int c   = (idx >> 5) * 2;
      float f0 = rp[(size_t)c * 4096 + p];
      float f1 = rp[(size_t)(c + 1) * 4096 + p];
      int m = si * 32 + p;
      unsigned off = ((unsigned)(m * 512 + c * 2)) ^ ((unsigned)(m & 7) << 4);
      *(unsigned*)(smem + off) = (unsigned)f2b(f0) | ((unsigned)f2b(f1) << 16);
    }
  }
  __syncthreads();   // only barrier in K1

  char* otile = o_ws + (size_t)blk * OTILE;
  const bf16x8* wfr = (const bf16x8*)wpack;
  const int ph = wv & 1;
  const int hg = wv >> 1;
  const float SC = 0.17677669529663687f;  // 1/sqrt(32)

  for (int hh = 0; hh < 4; ++hh) {
    const int h = hg * 4 + hh;
    f32x4 acc[3][6] = {};   // [token s][0,1=q 2,3=k 4,5=v]
#pragma unroll
    for (int ks = 0; ks < 8; ++ks) {
      const int k0 = ks * 32;
      bf16x8 af[3];
#pragma unroll
      for (int s = 0; s < 3; ++s) {
        int m = s * 32 + ph * 16 + l15;
        unsigned off = ((unsigned)(m * 512 + (k0 + l4 * 8) * 2)) ^ ((unsigned)(m & 7) << 4);
        af[s] = *(const bf16x8*)(smem + off);
      }
#pragma unroll
      for (int j = 0; j < 6; ++j) {
        int ntile = (j >> 1) * 16 + h * 2 + (j & 1);
        bf16x8 bfr = wfr[(ntile * 8 + ks) * 64 + lane];   // coalesced 1KB/inst
#pragma unroll
        for (int s = 0; s < 3; ++s)
          acc[s][j] = __builtin_amdgcn_mfma_f32_16x16x32_bf16(af[s], bfr, acc[s][j], 0, 0, 0);
      }
    }
    // bias (zeros here, kept for generality)
#pragma unroll
    for (int jq = 0; jq < 2; ++jq) {
      float bq = b_in[h * 32 + jq * 16 + l15];
      float bk = b_in[256 + h * 32 + jq * 16 + l15];
      float bv = b_in[512 + h * 32 + jq * 16 + l15];
#pragma unroll
      for (int s = 0; s < 3; ++s)
#pragma unroll
        for (int r = 0; r < 4; ++r) {
          acc[s][jq][r]     += bq;
          acc[s][2 + jq][r] += bk;
          acc[s][4 + jq][r] += bv;
        }
    }
    // in-register attention; lane holds d=jq*16+l15 of pixel p=ph*16+l4*4+r
#pragma unroll
    for (int si = 0; si < 3; ++si) {
      float pp[3][4];
#pragma unroll
      for (int ti = 0; ti < 3; ++ti)
#pragma unroll
        for (int r = 0; r < 4; ++r)
          pp[ti][r] = acc[si][0][r] * acc[ti][2][r] + acc[si][1][r] * acc[ti][3][r];
#pragma unroll
      for (int mask = 1; mask <= 8; mask <<= 1)
#pragma unroll
        for (int ti = 0; ti < 3; ++ti)
#pragma unroll
          for (int r = 0; r < 4; ++r)
            pp[ti][r] += __shfl_xor(pp[ti][r], mask);
#pragma unroll
      for (int r = 0; r < 4; ++r) {
        float s0 = pp[0][r] * SC, s1 = pp[1][r] * SC, s2 = pp[2][r] * SC;
        float mx = fmaxf(fmaxf(s0, s1), s2);
        float e0 = __expf(s0 - mx), e1 = __expf(s1 - mx), e2 = __expf(s2 - mx);
        float inv = 1.f / (e0 + e1 + e2);
        e0 *= inv; e1 *= inv; e2 *= inv;
        float ov0 = e0 * acc[0][4][r] + e1 * acc[1][4][r] + e2 * acc[2][4][r];
        float ov1 = e0 * acc[0][5][r] + e1 * acc[1][5][r] + e2 * acc[2][5][r];
        int m = si * 32 + ph * 16 + l4 * 4 + r;
        unsigned pk = (unsigned)f2b(ov0) | ((unsigned)f2b(ov1) << 16);
        *(unsigned*)(otile + h * 6144 + m * 64 + l15 * 4) = pk;  // 4x64B sectors/inst
      }
    }
  }
}

// ======= K2: stage o->LDS, out_proj, stage x->LDS, residual+LN, y->LDS, 1x1 conv =======
// LDS region A [0,49152): o [8][96][32], then x [96][256] swz, then y [32][768] swz.
#define PSOFF 49152
#define PQOFF 50688
#define MUOFF 52224
#define RSOFF 52608

__global__ __launch_bounds__(256, 3) void k2_proj_ln_conv(
    const float* __restrict__ cort,
    const float* __restrict__ subc,
    const float* __restrict__ vent,
    const char* __restrict__ o_ws,
    const __bf16* __restrict__ wpack_out,   // frag-packed, k-permuted
    const float* __restrict__ b_out,
    const float* __restrict__ gamma,
    const float* __restrict__ beta,
    const __bf16* __restrict__ wpack_conv,  // frag-packed
    const float* __restrict__ b_conv,
    float* __restrict__ out) {
  __shared__ char smem[52992];
  const int tid  = threadIdx.x;
  const int lane = tid & 63;
  const int wv   = tid >> 6;
  const int l15  = lane & 15;
  const int l4   = lane >> 4;
  const int blk  = blockIdx.x;
  const int img  = blk >> 7;
  const int pixbase = (blk & 127) << 5;
  const size_t base = (size_t)img * (256 * 4096) + pixbase;

  // stage o tile -> LDS, linear 16B copies
  {
    const char* src = o_ws + (size_t)blk * OTILE;
#pragma unroll
    for (int t = 0; t < 12; ++t) {
      int off = t * 4096 + tid * 16;
      *(bf16x8*)(smem + off) = *(const bf16x8*)(src + off);
    }
  }
  __syncthreads();   // B1

  // out_proj: y = o @ w_out^T; wave owns 64 N-cols; K-blocks = heads
  f32x4 accY[6][4] = {};
  const bf16x8* wob = (const bf16x8*)wpack_out;
#pragma unroll
  for (int h8 = 0; h8 < 8; ++h8) {
    bf16x8 af[6], bfr[4];
#pragma unroll
    for (int i = 0; i < 6; ++i)
      af[i] = *(const bf16x8*)(smem + h8 * 6144 + (i * 16 + l15) * 64 + l4 * 16);
#pragma unroll
    for (int j = 0; j < 4; ++j)
      bfr[j] = wob[((wv * 4 + j) * 8 + h8) * 64 + lane];
#pragma unroll
    for (int i = 0; i < 6; ++i)
#pragma unroll
      for (int j = 0; j < 4; ++j)
        accY[i][j] = __builtin_amdgcn_mfma_f32_16x16x32_bf16(af[i], bfr[j], accY[i][j], 0, 0, 0);
  }
  __syncthreads();   // B2: o reads done, region A reusable

  // stage x -> LDS bf16 swz (coalesced, same pattern as K1)
#pragma unroll
  for (int si = 0; si < 3; ++si) {
    const float* rp = (si == 0) ? cort : (si == 1) ? subc : vent;
    rp += base;
#pragma unroll
    for (int t = 0; t < 16; ++t) {
      int idx = t * 256 + tid;
      int p   = idx & 31;
      int c   = (idx >> 5) * 2;
      float f0 = rp[(size_t)c * 4096 + p];
      float f1 = rp[(size_t)(c + 1) * 4096 + p];
      int m = si * 32 + p;
      unsigned off = ((unsigned)(m * 512 + c * 2)) ^ ((unsigned)(m & 7) << 4);
      *(unsigned*)(smem + off) = (unsigned)f2b(f0) | ((unsigned)f2b(f1) << 16);
    }
  }
  __syncthreads();   // B3: x staged

  // bias + residual + LN partials
  float bo[4], gg[4], bb[4];
#pragma unroll
  for (int j = 0; j < 4; ++j) {
    int jc = wv * 64 + j * 16 + l15;
    bo[j] = b_out[jc];
    gg[j] = gamma[jc];
    bb[j] = beta[jc];
  }
#pragma unroll
  for (int i = 0; i < 6; ++i)
#pragma unroll
    for (int r = 0; r < 4; ++r) {
      int m = i * 16 + l4 * 4 + r;
      float s1 = 0.f, s2 = 0.f;
#pragma unroll
      for (int j = 0; j < 4; ++j) {
        int jc = wv * 64 + j * 16 + l15;
        unsigned xo = ((unsigned)(m * 512 + jc * 2)) ^ ((unsigned)(m & 7) << 4);
        float xv = (float)(*(const __bf16*)(smem + xo));
        float v = accY[i][j][r] + bo[j] + xv;
        accY[i][j][r] = v;
        s1 += v;
        s2 += v * v;
      }
      s1 += __shfl_xor(s1, 1); s2 += __shfl_xor(s2, 1);
      s1 += __shfl_xor(s1, 2); s2 += __shfl_xor(s2, 2);
      s1 += __shfl_xor(s1, 4); s2 += __shfl_xor(s2, 4);
      s1 += __shfl_xor(s1, 8); s2 += __shfl_xor(s2, 8);
      if (l15 == 0) {
        *(float*)(smem + PSOFF + (m * 4 + wv) * 4) = s1;
        *(float*)(smem + PQOFF + (m * 4 + wv) * 4) = s2;
      }
    }
  __syncthreads();   // B4
  if (tid < 96) {
    float s = 0.f, q = 0.f;
#pragma unroll
    for (int j = 0; j < 4; ++j) {
      s += *(const float*)(smem + PSOFF + (tid * 4 + j) * 4);
      q += *(const float*)(smem + PQOFF + (tid * 4 + j) * 4);
    }
    float mu  = s * (1.f / 256.f);
    float var = q * (1.f / 256.f) - mu * mu;
    *(float*)(smem + MUOFF + tid * 4) = mu;
    *(float*)(smem + RSOFF + tid * 4) = rsqrtf(var + 1e-5f);
  }
  __syncthreads();   // B5
  // rescale + write y bf16 [32][768] swz into region A (x dead)
#pragma unroll
  for (int i = 0; i < 6; ++i)
#pragma unroll
    for (int r = 0; r < 4; ++r) {
      int m = i * 16 + l4 * 4 + r;
      float mu = *(const float*)(smem + MUOFF + m * 4);
      float rs = *(const float*)(smem + RSOFF + m * 4);
      int s = m >> 5, p = m & 31;
#pragma unroll
      for (int j = 0; j < 4; ++j) {
        int jc = wv * 64 + j * 16 + l15;
        float yv = (accY[i][j][r] - mu) * rs * gg[j] + bb[j];
        int kk = s * 256 + jc;
        unsigned off = ((unsigned)(p * 1536 + kk * 2)) ^ ((unsigned)(p & 7) << 4);
        *(__bf16*)(smem + off) = (__bf16)yv;
      }
    }
  __syncthreads();   // B6

  // 1x1 conv: M=cout(256, wave owns 64), N=pixel(32), K=768
  {
    f32x4 accC[4][2] = {};
    const bf16x8* wcb = (const bf16x8*)wpack_conv;
#pragma unroll 4
    for (int ks = 0; ks < 24; ++ks) {
      const int k0 = ks * 32;
      bf16x8 af[4], bfr2[2];
#pragma unroll
      for (int i = 0; i < 4; ++i)
        af[i] = wcb[((wv * 4 + i) * 24 + ks) * 64 + lane];
#pragma unroll
      for (int j = 0; j < 2; ++j) {
        int p = j * 16 + l15;
        unsigned off = ((unsigned)(p * 1536 + (k0 + l4 * 8) * 2)) ^ ((unsigned)(p & 7) << 4);
        bfr2[j] = *(const bf16x8*)(smem + off);
      }
#pragma unroll
      for (int i = 0; i < 4; ++i)
#pragma unroll
        for (int j = 0; j < 2; ++j)
          accC[i][j] = __builtin_amdgcn_mfma_f32_16x16x32_bf16(af[i], bfr2[j], accC[i][j], 0, 0, 0);
    }
#pragma unroll
    for (int i = 0; i < 4; ++i)
#pragma unroll
      for (int r = 0; r < 4; ++r) {
        int co = wv * 64 + i * 16 + l4 * 4 + r;
        float cb = b_conv[co];
#pragma unroll
        for (int j = 0; j < 2; ++j)
          out[((size_t)img * 256 + co) * 4096 + pixbase + j * 16 + l15] = accC[i][j][r] + cb;
      }
  }
}

extern "C" void kernel_launch(void* const* d_in, const int* in_sizes, int n_in,
                              void* d_out, int out_size, void* d_ws, size_t ws_size,
                              hipStream_t stream) {
  (void)in_sizes; (void)n_in; (void)out_size; (void)ws_size;
  const float* cort    = (const float*)d_in[0];
  const float* subc    = (const float*)d_in[1];
  const float* vent    = (const float*)d_in[2];
  const float* w_in_f  = (const float*)d_in[3];
  const float* b_in    = (const float*)d_in[4];
  const float* w_out_f = (const float*)d_in[5];
  const float* b_out   = (const float*)d_in[6];
  const float* gamma   = (const float*)d_in[7];
  const float* beta    = (const float*)d_in[8];
  const float* w_conv_f= (const float*)d_in[9];
  const float* b_conv  = (const float*)d_in[10];

  __bf16* wsb = (__bf16*)d_ws;              // packed weights: 917504 B
  char*   o_ws = (char*)d_ws + (1 << 20);   // o: 1024*49152 = 50331648 B

  repack_weights<<<224, 256, 0, stream>>>(w_in_f, w_out_f, w_conv_f, wsb);
  k1_qkv_attn<<<1024, 256, 0, stream>>>(cort, subc, vent, wsb, b_in, o_ws);
  k2_proj_ln_conv<<<1024, 256, 0, stream>>>(cort, subc, vent, o_ws,
                                            wsb + 196608, b_out, gamma, beta,
                                            wsb + 262144, b_conv, (float*)d_out);
}

// Round 10
// 265.908 us; speedup vs baseline: 1.3741x; 1.3741x over previous
//
#include <hip/hip_runtime.h>

typedef __bf16 bf16x8 __attribute__((ext_vector_type(8)));
typedef float  f32x4  __attribute__((ext_vector_type(4)));

// ---- LDS layout (bytes) ----  (identical to the 204us round-3 kernel)
// x : [96][256] bf16 swz  off=(m*512+2c)^((m&7)<<4)           [0,49152)
//     later y: [32][768] bf16 swz off=(p*1536+2k)^((p&7)<<4)   aliases x
// o : [2][96][40] bf16 padded (row stride 80B)                 [49152,64512)
// ps: [96][4] f32  pq: [96][4] f32  mu/rs: [96] f32
#define XOFF 0
#define OOFF 49152
#define OBUFSZ 7680
#define PSOFF 64512
#define PQOFF 66048
#define MUOFF 67584
#define RSOFF 67968
#define SMEM_BYTES 68352

static __device__ __forceinline__ unsigned short f2b(float f) {
  __bf16 h = (__bf16)f;
  return __builtin_bit_cast(unsigned short, h);
}

// ---- repack weights into MFMA-fragment-linear bf16 tiles (natural k order) ----
// w_in  -> [48 nt][ 8 ks][64 lane][8]  elems 0..196607       (nt: row-tile of 3C x C)
// w_out -> [16 nt][ 8 ks][64 lane][8]  elems 196608..262143
// w_conv-> [16 nt][24 ks][64 lane][8]  elems 262144..458751
// fragment for (nt,ks): lane (l15,l4) holds rows nt*16+l15, k = ks*32 + l4*8 .. +8
__global__ void repack_weights(const float* __restrict__ w_in,
                               const float* __restrict__ w_out,
                               const float* __restrict__ w_conv,
                               __bf16* __restrict__ ws) {
  int g = blockIdx.x * 256 + threadIdx.x;   // granule id, 0..57343
  __bf16* dst = ws + (size_t)g * 8;
  const float* src;
  if (g < 24576) {                          // w_in: nt<48, ks<8
    int nt = g >> 9, rem = g & 511;
    int ks = rem >> 6, lane = rem & 63;
    src = w_in + (size_t)(nt * 16 + (lane & 15)) * 256 + ks * 32 + (lane >> 4) * 8;
  } else if (g < 32768) {                   // w_out: nt<16, ks<8
    int g2 = g - 24576;
    int nt = g2 >> 9, rem = g2 & 511;
    int ks = rem >> 6, lane = rem & 63;
    src = w_out + (size_t)(nt * 16 + (lane & 15)) * 256 + ks * 32 + (lane >> 4) * 8;
  } else {                                  // w_conv: nt<16, ks<24
    int g3 = g - 32768;
    int nt = g3 / 1536, rem = g3 - nt * 1536;
    int ks = rem >> 6, lane = rem & 63;
    src = w_conv + (size_t)(nt * 16 + (lane & 15)) * 768 + ks * 32 + (lane >> 4) * 8;
  }
  float4 a = *(const float4*)src;
  float4 b = *(const float4*)(src + 4);
  dst[0]=(__bf16)a.x; dst[1]=(__bf16)a.y; dst[2]=(__bf16)a.z; dst[3]=(__bf16)a.w;
  dst[4]=(__bf16)b.x; dst[5]=(__bf16)b.y; dst[6]=(__bf16)b.z; dst[7]=(__bf16)b.w;
}

__global__ __launch_bounds__(256, 2) void crf_fused(
    const float* __restrict__ cort,
    const float* __restrict__ subc,
    const float* __restrict__ vent,
    const __bf16* __restrict__ w_in,     // frag-packed
    const float* __restrict__ b_in,
    const __bf16* __restrict__ w_out,    // frag-packed
    const float* __restrict__ b_out,
    const float* __restrict__ gamma,
    const float* __restrict__ beta,
    const __bf16* __restrict__ w_conv,   // frag-packed
    const float* __restrict__ b_conv,
    float* __restrict__ out) {
  extern __shared__ char smem[];
  const int tid  = threadIdx.x;
  const int lane = tid & 63;
  const int wv   = tid >> 6;
  const int l15  = lane & 15;
  const int l4   = lane >> 4;
  const int blk  = blockIdx.x;
  const int img  = blk >> 7;                 // 128 blocks per image
  const int pixbase = (blk & 127) << 5;      // 32 pixels per block
  const size_t base = (size_t)img * (256 * 4096) + pixbase;

  // ---------- stage x -> LDS bf16 [96][256] swizzled (128B-aligned global reads) ----------
  {
    const float* rp0 = cort + base;
    const float* rp1 = subc + base;
    const float* rp2 = vent + base;
#pragma unroll
    for (int si = 0; si < 3; ++si) {
      const float* rp = (si == 0) ? rp0 : (si == 1) ? rp1 : rp2;
#pragma unroll
      for (int t = 0; t < 16; ++t) {
        int idx = t * 256 + tid;        // 0..4095
        int p   = idx & 31;
        int c   = (idx >> 5) * 2;       // even channel
        float f0 = rp[(size_t)c * 4096 + p];
        float f1 = rp[(size_t)(c + 1) * 4096 + p];
        int m = si * 32 + p;
        unsigned off = ((unsigned)(m * 512 + c * 2)) ^ ((unsigned)(m & 7) << 4);
        unsigned pack = (unsigned)f2b(f0) | ((unsigned)f2b(f1) << 16);
        *(unsigned*)(smem + XOFF + off) = pack;
      }
    }
  }

  f32x4 accY[6][4] = {};   // persistent out_proj accumulators: wave owns 64 N-cols, all 96 M-rows

  __syncthreads();   // B1

  const int ph = wv & 1;   // pixel half (16 pixels)
  const int hg = wv >> 1;  // head group (4 heads)
  const float SC = 0.17677669529663687f;  // 1/sqrt(32)
  const bf16x8* wif = (const bf16x8*)w_in;
  const bf16x8* wof = (const bf16x8*)w_out;
  const bf16x8* wcf = (const bf16x8*)w_conv;

  for (int hh = 0; hh < 4; ++hh) {
    const int h = hg * 4 + hh;
    // ---------- QKV GEMM for head h, this wave's 16 pixels (3 token tiles) ----------
    f32x4 acc[3][6] = {};   // [token s][0,1=q 2,3=k 4,5=v]
#pragma unroll
    for (int ks = 0; ks < 8; ++ks) {
      const int k0 = ks * 32;
      bf16x8 af[3], bfr[6];
#pragma unroll
      for (int s = 0; s < 3; ++s) {
        int m = s * 32 + ph * 16 + l15;
        unsigned off = ((unsigned)(m * 512 + (k0 + l4 * 8) * 2)) ^ ((unsigned)(m & 7) << 4);
        af[s] = *(const bf16x8*)(smem + XOFF + off);
      }
#pragma unroll
      for (int j = 0; j < 6; ++j) {
        int nt = (j >> 1) * 16 + h * 2 + (j & 1);       // row-tile of w_in
        bfr[j] = wif[(nt * 8 + ks) * 64 + lane];        // coalesced 1KB fragment load
      }
#pragma unroll
      for (int s = 0; s < 3; ++s)
#pragma unroll
        for (int j = 0; j < 6; ++j)
          acc[s][j] = __builtin_amdgcn_mfma_f32_16x16x32_bf16(af[s], bfr[j], acc[s][j], 0, 0, 0);
    }
    // bias add in place (lane l15 = channel within 16-col tile)
#pragma unroll
    for (int jq = 0; jq < 2; ++jq) {
      float bq = b_in[h * 32 + jq * 16 + l15];
      float bk = b_in[256 + h * 32 + jq * 16 + l15];
      float bv = b_in[512 + h * 32 + jq * 16 + l15];
#pragma unroll
      for (int s = 0; s < 3; ++s)
#pragma unroll
        for (int r = 0; r < 4; ++r) {
          acc[s][jq][r]     += bq;
          acc[s][2 + jq][r] += bk;
          acc[s][4 + jq][r] += bv;
        }
    }
    // ---------- in-register attention; lane holds d=jq*16+l15 for pixel p=ph*16+l4*4+r ----------
    char* ob = smem + OOFF + hg * OBUFSZ;
#pragma unroll
    for (int si = 0; si < 3; ++si) {
      float pp[3][4];
#pragma unroll
      for (int ti = 0; ti < 3; ++ti)
#pragma unroll
        for (int r = 0; r < 4; ++r)
          pp[ti][r] = acc[si][0][r] * acc[ti][2][r] + acc[si][1][r] * acc[ti][3][r];
#pragma unroll
      for (int mask = 1; mask <= 8; mask <<= 1)
#pragma unroll
        for (int ti = 0; ti < 3; ++ti)
#pragma unroll
          for (int r = 0; r < 4; ++r)
            pp[ti][r] += __shfl_xor(pp[ti][r], mask);
#pragma unroll
      for (int r = 0; r < 4; ++r) {
        float s0 = pp[0][r] * SC, s1 = pp[1][r] * SC, s2 = pp[2][r] * SC;
        float mx = fmaxf(fmaxf(s0, s1), s2);
        float e0 = __expf(s0 - mx), e1 = __expf(s1 - mx), e2 = __expf(s2 - mx);
        float inv = 1.f / (e0 + e1 + e2);
        e0 *= inv; e1 *= inv; e2 *= inv;
        int m = si * 32 + ph * 16 + l4 * 4 + r;
#pragma unroll
        for (int jq = 0; jq < 2; ++jq) {
          float ov = e0 * acc[0][4 + jq][r] + e1 * acc[1][4 + jq][r] + e2 * acc[2][4 + jq][r];
          *(__bf16*)(ob + m * 80 + (jq * 16 + l15) * 2) = (__bf16)ov;
        }
      }
    }
    __syncthreads();   // o tiles (both head groups) complete

    // ---------- out_proj partial: accY += o_g @ w_out[:, hB*32:+32]^T for g=0,1 ----------
#pragma unroll
    for (int g = 0; g < 2; ++g) {
      const char* obr = smem + OOFF + g * OBUFSZ;
      const int hB = g * 4 + hh;
      bf16x8 af2[6], bf2[4];
#pragma unroll
      for (int i = 0; i < 6; ++i)
        af2[i] = *(const bf16x8*)(obr + (i * 16 + l15) * 80 + l4 * 16);
#pragma unroll
      for (int j = 0; j < 4; ++j)
        bf2[j] = wof[((wv * 4 + j) * 8 + hB) * 64 + lane];   // packed fragment
#pragma unroll
      for (int i = 0; i < 6; ++i)
#pragma unroll
        for (int j = 0; j < 4; ++j)
          accY[i][j] = __builtin_amdgcn_mfma_f32_16x16x32_bf16(af2[i], bf2[j], accY[i][j], 0, 0, 0);
    }
    __syncthreads();   // reads done before next head's o writes
  }  // head loop

  // ---------- bias + residual + LayerNorm partials ----------
  float bo[4], gg[4], bb2[4];
#pragma unroll
  for (int j = 0; j < 4; ++j) {
    int jc = wv * 64 + j * 16 + l15;
    bo[j] = b_out[jc];
    gg[j] = gamma[jc];
    bb2[j] = beta[jc];
  }
#pragma unroll
  for (int i = 0; i < 6; ++i)
#pragma unroll
    for (int r = 0; r < 4; ++r) {
      int m = i * 16 + l4 * 4 + r;
      float s1 = 0.f, s2 = 0.f;
#pragma unroll
      for (int j = 0; j < 4; ++j) {
        int jc = wv * 64 + j * 16 + l15;
        unsigned xo = ((unsigned)(m * 512 + jc * 2)) ^ ((unsigned)(m & 7) << 4);
        float xv = (float)(*(const __bf16*)(smem + XOFF + xo));
        float v = accY[i][j][r] + bo[j] + xv;
        accY[i][j][r] = v;
        s1 += v;
        s2 += v * v;
      }
      s1 += __shfl_xor(s1, 1); s2 += __shfl_xor(s2, 1);
      s1 += __shfl_xor(s1, 2); s2 += __shfl_xor(s2, 2);
      s1 += __shfl_xor(s1, 4); s2 += __shfl_xor(s2, 4);
      s1 += __shfl_xor(s1, 8); s2 += __shfl_xor(s2, 8);
      if (l15 == 0) {
        *(float*)(smem + PSOFF + (m * 4 + wv) * 4) = s1;
        *(float*)(smem + PQOFF + (m * 4 + wv) * 4) = s2;
      }
    }
  __syncthreads();
  if (tid < 96) {
    float s = 0.f, q = 0.f;
#pragma unroll
    for (int j = 0; j < 4; ++j) {
      s += *(const float*)(smem + PSOFF + (tid * 4 + j) * 4);
      q += *(const float*)(smem + PQOFF + (tid * 4 + j) * 4);
    }
    float mu  = s * (1.f / 256.f);
    float var = q * (1.f / 256.f) - mu * mu;
    *(float*)(smem + MUOFF + tid * 4) = mu;
    *(float*)(smem + RSOFF + tid * 4) = rsqrtf(var + 1e-5f);
  }
  __syncthreads();
  // rescale + write y bf16 into [32][768] swz (aliases x; all x reads done)
#pragma unroll
  for (int i = 0; i < 6; ++i)
#pragma unroll
    for (int r = 0; r < 4; ++r) {
      int m = i * 16 + l4 * 4 + r;
      float mu = *(const float*)(smem + MUOFF + m * 4);
      float rs = *(const float*)(smem + RSOFF + m * 4);
      int s = m >> 5, p = m & 31;
#pragma unroll
      for (int j = 0; j < 4; ++j) {
        int jc = wv * 64 + j * 16 + l15;
        float yv = (accY[i][j][r] - mu) * rs * gg[j] + bb2[j];
        int kk = s * 256 + jc;
        unsigned off = ((unsigned)(p * 1536 + kk * 2)) ^ ((unsigned)(p & 7) << 4);
        *(__bf16*)(smem + XOFF + off) = (__bf16)yv;
      }
    }
  __syncthreads();

  // ---------- 1x1 conv: M=cout(256, wave owns 64), N=pixel(32), K=768 ----------
  {
    f32x4 accC[4][2] = {};
#pragma unroll 4
    for (int ks = 0; ks < 24; ++ks) {
      const int k0 = ks * 32;
      bf16x8 af[4], bfr2[2];
#pragma unroll
      for (int i = 0; i < 4; ++i)
        af[i] = wcf[((wv * 4 + i) * 24 + ks) * 64 + lane];   // packed fragment
#pragma unroll
      for (int j = 0; j < 2; ++j) {
        int p = j * 16 + l15;
        unsigned off = ((unsigned)(p * 1536 + (k0 + l4 * 8) * 2)) ^ ((unsigned)(p & 7) << 4);
        bfr2[j] = *(const bf16x8*)(smem + XOFF + off);
      }
#pragma unroll
      for (int i = 0; i < 4; ++i)
#pragma unroll
        for (int j = 0; j < 2; ++j)
          accC[i][j] = __builtin_amdgcn_mfma_f32_16x16x32_bf16(af[i], bfr2[j], accC[i][j], 0, 0, 0);
    }
#pragma unroll
    for (int i = 0; i < 4; ++i)
#pragma unroll
      for (int r = 0; r < 4; ++r) {
        int co = wv * 64 + i * 16 + l4 * 4 + r;
        float cb = b_conv[co];
#pragma unroll
        for (int j = 0; j < 2; ++j)
          out[((size_t)img * 256 + co) * 4096 + pixbase + j * 16 + l15] = accC[i][j][r] + cb;
      }
  }
}

extern "C" void kernel_launch(void* const* d_in, const int* in_sizes, int n_in,
                              void* d_out, int out_size, void* d_ws, size_t ws_size,
                              hipStream_t stream) {
  (void)in_sizes; (void)n_in; (void)out_size; (void)ws_size;
  const float* cort    = (const float*)d_in[0];
  const float* subc    = (const float*)d_in[1];
  const float* vent    = (const float*)d_in[2];
  const float* w_in_f  = (const float*)d_in[3];
  const float* b_in    = (const float*)d_in[4];
  const float* w_out_f = (const float*)d_in[5];
  const float* b_out   = (const float*)d_in[6];
  const float* gamma   = (const float*)d_in[7];
  const float* beta    = (const float*)d_in[8];
  const float* w_conv_f= (const float*)d_in[9];
  const float* b_conv  = (const float*)d_in[10];

  __bf16* ws = (__bf16*)d_ws;   // packed weights: 458752 bf16 = 917504 B
  repack_weights<<<224, 256, 0, stream>>>(w_in_f, w_out_f, w_conv_f, ws);
  crf_fused<<<1024, 256, SMEM_BYTES, stream>>>(
      cort, subc, vent,
      ws,            b_in,
      ws + 196608,   b_out,
      gamma,         beta,
      ws + 262144,   b_conv,
      (float*)d_out);
}

// Round 11
// 215.159 us; speedup vs baseline: 1.6982x; 1.2359x over previous
//
#include <hip/hip_runtime.h>

typedef __bf16 bf16x8 __attribute__((ext_vector_type(8)));
typedef float  f32x4  __attribute__((ext_vector_type(4)));

// ---- LDS layout (bytes), 512-thread block, 32 pixels ----
// x : [96][256] bf16 swz off=(m*512+2c)^((m&7)<<4)           [0,49152)
//     later y: [32][768] bf16 swz off=(p*1536+2k)^((p&7)<<4)  aliases x (written after all x reads)
// o : [96][256] bf16 swz (same swizzle as x)                  [49152,98304)
// ps: [96][8] f32   pq: [96][8] f32   mu/rs: [96] f32
#define XOFF 0
#define OOFF 49152
#define PSOFF 98304
#define PQOFF 101376
#define MUOFF 104448
#define RSOFF 104832
#define SMEM_BYTES 105216

static __device__ __forceinline__ unsigned short f2b(float f) {
  __bf16 h = (__bf16)f;
  return __builtin_bit_cast(unsigned short, h);
}

// simple 1:1 cast to bf16, row-major (proven r1-r8; NOT the packed layout)
__global__ void convert_weights(const float* __restrict__ w_in,
                                const float* __restrict__ w_out,
                                const float* __restrict__ w_conv,
                                __bf16* __restrict__ ws) {
  int gid = blockIdx.x * 256 + threadIdx.x;   // 0..114687
  int i4 = gid * 4;
  const float* src;
  int off;
  if (i4 < 196608)      { src = w_in;   off = i4; }
  else if (i4 < 262144) { src = w_out;  off = i4 - 196608; }
  else                  { src = w_conv; off = i4 - 262144; }
  float4 f = *(const float4*)(src + off);
  ws[i4 + 0] = (__bf16)f.x;
  ws[i4 + 1] = (__bf16)f.y;
  ws[i4 + 2] = (__bf16)f.z;
  ws[i4 + 3] = (__bf16)f.w;
}

__global__ __launch_bounds__(512, 2) void crf_fused(
    const float* __restrict__ cort,
    const float* __restrict__ subc,
    const float* __restrict__ vent,
    const __bf16* __restrict__ w_in,
    const float* __restrict__ b_in,
    const __bf16* __restrict__ w_out,
    const float* __restrict__ b_out,
    const float* __restrict__ gamma,
    const float* __restrict__ beta,
    const __bf16* __restrict__ w_conv,
    const float* __restrict__ b_conv,
    float* __restrict__ out) {
  extern __shared__ char smem[];
  const int tid  = threadIdx.x;
  const int lane = tid & 63;
  const int wv   = tid >> 6;          // 0..7  == head for QKV phase
  const int l15  = lane & 15;
  const int l4   = lane >> 4;
  const int blk  = blockIdx.x;
  const int img  = blk >> 7;                 // 128 blocks per image
  const int pixbase = (blk & 127) << 5;      // 32 pixels per block
  const size_t base = (size_t)img * (256 * 4096) + pixbase;

  // ---------- stage x -> LDS bf16 [96][256] swizzled (128B-aligned global reads) ----------
  {
#pragma unroll
    for (int si = 0; si < 3; ++si) {
      const float* rp = (si == 0) ? cort : (si == 1) ? subc : vent;
      rp += base;
#pragma unroll
      for (int t = 0; t < 8; ++t) {
        int idx = t * 512 + tid;        // 0..4095
        int p   = idx & 31;
        int c   = (idx >> 5) * 2;       // even channel
        float f0 = rp[(size_t)c * 4096 + p];
        float f1 = rp[(size_t)(c + 1) * 4096 + p];
        int m = si * 32 + p;
        unsigned off = ((unsigned)(m * 512 + c * 2)) ^ ((unsigned)(m & 7) << 4);
        *(unsigned*)(smem + XOFF + off) = (unsigned)f2b(f0) | ((unsigned)f2b(f1) << 16);
      }
    }
  }
  __syncthreads();   // B1

  // ---------- QKV GEMM: wave = head wv, ALL 32 pixels (no weight duplication) ----------
  {
    const int h = wv;
    const float SC = 0.17677669529663687f;  // 1/sqrt(32)
    f32x4 acc[6][6] = {};   // [M-tile mi][0,1=q 2,3=k 4,5=v] : 144 VGPR
#pragma unroll
    for (int ks = 0; ks < 8; ++ks) {
      const int k0 = ks * 32;
      bf16x8 af[6], bfr[6];
#pragma unroll
      for (int mi = 0; mi < 6; ++mi) {
        int m = mi * 16 + l15;
        unsigned off = ((unsigned)(m * 512 + (k0 + l4 * 8) * 2)) ^ ((unsigned)(m & 7) << 4);
        af[mi] = *(const bf16x8*)(smem + XOFF + off);
      }
#pragma unroll
      for (int j = 0; j < 6; ++j) {
        int jb = (j >> 1) * 256 + h * 32 + (j & 1) * 16 + l15;
        bfr[j] = *(const bf16x8*)(w_in + (size_t)jb * 256 + k0 + l4 * 8);
      }
#pragma unroll
      for (int mi = 0; mi < 6; ++mi)
#pragma unroll
        for (int j = 0; j < 6; ++j)
          acc[mi][j] = __builtin_amdgcn_mfma_f32_16x16x32_bf16(af[mi], bfr[j], acc[mi][j], 0, 0, 0);
    }
    // bias add (zeros here, kept for generality)
#pragma unroll
    for (int jq = 0; jq < 2; ++jq) {
      float bq = b_in[h * 32 + jq * 16 + l15];
      float bk = b_in[256 + h * 32 + jq * 16 + l15];
      float bv = b_in[512 + h * 32 + jq * 16 + l15];
#pragma unroll
      for (int mi = 0; mi < 6; ++mi)
#pragma unroll
        for (int r = 0; r < 4; ++r) {
          acc[mi][jq][r]     += bq;
          acc[mi][2 + jq][r] += bk;
          acc[mi][4 + jq][r] += bv;
        }
    }
    // ---------- in-register attention ----------
    // lane holds, for pixel p = pg*16 + l4*4 + r (pg = mi&1), token s (mi = 2s+pg):
    //   q/k/v[d = jq*16 + l15] in acc[2s+pg][jq / 2+jq / 4+jq][r]
#pragma unroll
    for (int pg = 0; pg < 2; ++pg) {
#pragma unroll
      for (int si = 0; si < 3; ++si) {
        float pp[3][4];
#pragma unroll
        for (int ti = 0; ti < 3; ++ti)
#pragma unroll
          for (int r = 0; r < 4; ++r)
            pp[ti][r] = acc[2 * si + pg][0][r] * acc[2 * ti + pg][2][r]
                      + acc[2 * si + pg][1][r] * acc[2 * ti + pg][3][r];
#pragma unroll
        for (int mask = 1; mask <= 8; mask <<= 1)
#pragma unroll
          for (int ti = 0; ti < 3; ++ti)
#pragma unroll
            for (int r = 0; r < 4; ++r)
              pp[ti][r] += __shfl_xor(pp[ti][r], mask);
#pragma unroll
        for (int r = 0; r < 4; ++r) {
          float s0 = pp[0][r] * SC, s1 = pp[1][r] * SC, s2 = pp[2][r] * SC;
          float mx = fmaxf(fmaxf(s0, s1), s2);
          float e0 = __expf(s0 - mx), e1 = __expf(s1 - mx), e2 = __expf(s2 - mx);
          float inv = 1.f / (e0 + e1 + e2);
          e0 *= inv; e1 *= inv; e2 *= inv;
          int m = si * 32 + pg * 16 + l4 * 4 + r;
#pragma unroll
          for (int jq = 0; jq < 2; ++jq) {
            float ov = e0 * acc[pg][4 + jq][r] + e1 * acc[2 + pg][4 + jq][r] + e2 * acc[4 + pg][4 + jq][r];
            int d = h * 32 + jq * 16 + l15;
            unsigned off = ((unsigned)(m * 512 + d * 2)) ^ ((unsigned)(m & 7) << 4);
            *(__bf16*)(smem + OOFF + off) = (__bf16)ov;
          }
        }
      }
    }
  }
  __syncthreads();   // B2: o[96][256] complete (acc dead)

  // ---------- out_proj: wave owns 32 N-cols; accY[6][2] = 48 regs ----------
  f32x4 accY[6][2] = {};
#pragma unroll
  for (int ks = 0; ks < 8; ++ks) {
    const int k0 = ks * 32;
    bf16x8 af[6], bfr[2];
#pragma unroll
    for (int i = 0; i < 6; ++i) {
      int m = i * 16 + l15;
      unsigned off = ((unsigned)(m * 512 + (k0 + l4 * 8) * 2)) ^ ((unsigned)(m & 7) << 4);
      af[i] = *(const bf16x8*)(smem + OOFF + off);
    }
#pragma unroll
    for (int j = 0; j < 2; ++j) {
      int jr = wv * 32 + j * 16 + l15;
      bfr[j] = *(const bf16x8*)(w_out + (size_t)jr * 256 + k0 + l4 * 8);
    }
#pragma unroll
    for (int i = 0; i < 6; ++i)
#pragma unroll
      for (int j = 0; j < 2; ++j)
        accY[i][j] = __builtin_amdgcn_mfma_f32_16x16x32_bf16(af[i], bfr[j], accY[i][j], 0, 0, 0);
  }

  // ---------- bias + residual + LayerNorm partials (wave owns 32 cols) ----------
  float bo[2], gg[2], bb[2];
#pragma unroll
  for (int j = 0; j < 2; ++j) {
    int jc = wv * 32 + j * 16 + l15;
    bo[j] = b_out[jc];
    gg[j] = gamma[jc];
    bb[j] = beta[jc];
  }
#pragma unroll
  for (int i = 0; i < 6; ++i)
#pragma unroll
    for (int r = 0; r < 4; ++r) {
      int m = i * 16 + l4 * 4 + r;
      float s1 = 0.f, s2 = 0.f;
#pragma unroll
      for (int j = 0; j < 2; ++j) {
        int jc = wv * 32 + j * 16 + l15;
        unsigned xo = ((unsigned)(m * 512 + jc * 2)) ^ ((unsigned)(m & 7) << 4);
        float xv = (float)(*(const __bf16*)(smem + XOFF + xo));
        float v = accY[i][j][r] + bo[j] + xv;
        accY[i][j][r] = v;
        s1 += v;
        s2 += v * v;
      }
      s1 += __shfl_xor(s1, 1); s2 += __shfl_xor(s2, 1);
      s1 += __shfl_xor(s1, 2); s2 += __shfl_xor(s2, 2);
      s1 += __shfl_xor(s1, 4); s2 += __shfl_xor(s2, 4);
      s1 += __shfl_xor(s1, 8); s2 += __shfl_xor(s2, 8);
      if (l15 == 0) {
        *(float*)(smem + PSOFF + (m * 8 + wv) * 4) = s1;
        *(float*)(smem + PQOFF + (m * 8 + wv) * 4) = s2;
      }
    }
  __syncthreads();   // B3
  if (tid < 96) {
    float s = 0.f, q = 0.f;
#pragma unroll
    for (int j = 0; j < 8; ++j) {
      s += *(const float*)(smem + PSOFF + (tid * 8 + j) * 4);
      q += *(const float*)(smem + PQOFF + (tid * 8 + j) * 4);
    }
    float mu  = s * (1.f / 256.f);
    float var = q * (1.f / 256.f) - mu * mu;
    *(float*)(smem + MUOFF + tid * 4) = mu;
    *(float*)(smem + RSOFF + tid * 4) = rsqrtf(var + 1e-5f);
  }
  __syncthreads();   // B4
  // rescale + write y bf16 into [32][768] swz (aliases x; all x reads done)
#pragma unroll
  for (int i = 0; i < 6; ++i)
#pragma unroll
    for (int r = 0; r < 4; ++r) {
      int m = i * 16 + l4 * 4 + r;
      float mu = *(const float*)(smem + MUOFF + m * 4);
      float rs = *(const float*)(smem + RSOFF + m * 4);
      int s = m >> 5, p = m & 31;
#pragma unroll
      for (int j = 0; j < 2; ++j) {
        int jc = wv * 32 + j * 16 + l15;
        float yv = (accY[i][j][r] - mu) * rs * gg[j] + bb[j];
        int kk = s * 256 + jc;
        unsigned off = ((unsigned)(p * 1536 + kk * 2)) ^ ((unsigned)(p & 7) << 4);
        *(__bf16*)(smem + XOFF + off) = (__bf16)yv;
      }
    }
  __syncthreads();   // B5

  // ---------- 1x1 conv: wave owns 32 cout; N=32 pixels; K=768 ----------
  {
    f32x4 accC[2][2] = {};
#pragma unroll 4
    for (int ks = 0; ks < 24; ++ks) {
      const int k0 = ks * 32;
      bf16x8 af[2], bfr2[2];
#pragma unroll
      for (int i = 0; i < 2; ++i) {
        int co = wv * 32 + i * 16 + l15;
        af[i] = *(const bf16x8*)(w_conv + (size_t)co * 768 + k0 + l4 * 8);
      }
#pragma unroll
      for (int j = 0; j < 2; ++j) {
        int p = j * 16 + l15;
        unsigned off = ((unsigned)(p * 1536 + (k0 + l4 * 8) * 2)) ^ ((unsigned)(p & 7) << 4);
        bfr2[j] = *(const bf16x8*)(smem + XOFF + off);
      }
#pragma unroll
      for (int i = 0; i < 2; ++i)
#pragma unroll
        for (int j = 0; j < 2; ++j)
          accC[i][j] = __builtin_amdgcn_mfma_f32_16x16x32_bf16(af[i], bfr2[j], accC[i][j], 0, 0, 0);
    }
#pragma unroll
    for (int i = 0; i < 2; ++i)
#pragma unroll
      for (int r = 0; r < 4; ++r) {
        int co = wv * 32 + i * 16 + l4 * 4 + r;
        float cb = b_conv[co];
#pragma unroll
        for (int j = 0; j < 2; ++j)
          out[((size_t)img * 256 + co) * 4096 + pixbase + j * 16 + l15] = accC[i][j][r] + cb;
      }
  }
}

extern "C" void kernel_launch(void* const* d_in, const int* in_sizes, int n_in,
                              void* d_out, int out_size, void* d_ws, size_t ws_size,
                              hipStream_t stream) {
  (void)in_sizes; (void)n_in; (void)out_size; (void)ws_size;
  const float* cort    = (const float*)d_in[0];
  const float* subc    = (const float*)d_in[1];
  const float* vent    = (const float*)d_in[2];
  const float* w_in_f  = (const float*)d_in[3];
  const float* b_in    = (const float*)d_in[4];
  const float* w_out_f = (const float*)d_in[5];
  const float* b_out   = (const float*)d_in[6];
  const float* gamma   = (const float*)d_in[7];
  const float* beta    = (const float*)d_in[8];
  const float* w_conv_f= (const float*)d_in[9];
  const float* b_conv  = (const float*)d_in[10];

  __bf16* ws = (__bf16*)d_ws;   // 458752 bf16 = 917504 B
  convert_weights<<<448, 256, 0, stream>>>(w_in_f, w_out_f, w_conv_f, ws);
  crf_fused<<<1024, 512, SMEM_BYTES, stream>>>(
      cort, subc, vent,
      ws,            b_in,
      ws + 196608,   b_out,
      gamma,         beta,
      ws + 262144,   b_conv,
      (float*)d_out);
}

// Round 12
// 200.470 us; speedup vs baseline: 1.8226x; 1.0733x over previous
//
#include <hip/hip_runtime.h>

typedef __bf16 bf16x8 __attribute__((ext_vector_type(8)));
typedef float  f32x4  __attribute__((ext_vector_type(4)));

// ---- LDS layout (bytes) ----
// x : [96][256] bf16 swz  off=(m*512+2c)^((m&31)<<4)          [0,49152)
//     later y: [32][768] bf16 swz off=(p*1536+2k)^((p&31)<<4)  aliases x
// o : [2 hg][2 buf][96][40] bf16 (80B rows, 16B-aligned)       [49152,79872)
// after head loop (o dead): ps [96][4] f32 @49152, pq @50688, mu @52224, rs @52608
#define XOFF 0
#define OOFF 49152
#define OBUFSZ 7680
#define PSOFF 49152
#define PQOFF 50688
#define MUOFF 52224
#define RSOFF 52608
#define SMEM_BYTES 79872
#define OB(g,b) (smem + OOFF + ((g) * 2 + (b)) * OBUFSZ)

static __device__ __forceinline__ unsigned short f2b(float f) {
  __bf16 h = (__bf16)f;
  return __builtin_bit_cast(unsigned short, h);
}

__global__ void convert_weights(const float* __restrict__ w_in,
                                const float* __restrict__ w_out,
                                const float* __restrict__ w_conv,
                                __bf16* __restrict__ ws) {
  int gid = blockIdx.x * 256 + threadIdx.x;   // 0..114687
  int i4 = gid * 4;
  const float* src;
  int off;
  if (i4 < 196608)      { src = w_in;   off = i4; }
  else if (i4 < 262144) { src = w_out;  off = i4 - 196608; }
  else                  { src = w_conv; off = i4 - 262144; }
  float4 f = *(const float4*)(src + off);
  ws[i4 + 0] = (__bf16)f.x;
  ws[i4 + 1] = (__bf16)f.y;
  ws[i4 + 2] = (__bf16)f.z;
  ws[i4 + 3] = (__bf16)f.w;
}

__global__ __launch_bounds__(256, 2) void crf_fused(
    const float* __restrict__ cort,
    const float* __restrict__ subc,
    const float* __restrict__ vent,
    const __bf16* __restrict__ w_in,
    const float* __restrict__ b_in,
    const __bf16* __restrict__ w_out,
    const float* __restrict__ b_out,
    const float* __restrict__ gamma,
    const float* __restrict__ beta,
    const __bf16* __restrict__ w_conv,
    const float* __restrict__ b_conv,
    float* __restrict__ out) {
  extern __shared__ char smem[];
  const int tid  = threadIdx.x;
  const int lane = tid & 63;
  const int wv   = tid >> 6;
  const int l15  = lane & 15;
  const int l4   = lane >> 4;
  const int blk  = blockIdx.x;
  const int img  = blk >> 7;                 // 128 blocks per image
  const int pixbase = (blk & 127) << 5;      // 32 pixels per block
  const size_t base = (size_t)img * (256 * 4096) + pixbase;

  // ---------- stage x -> LDS bf16 [96][256] swz; float4 reads, packed dword writes ----------
  {
    const int p4 = (tid & 7) * 4;           // pixel quad
#pragma unroll
    for (int si = 0; si < 3; ++si) {
      const float* rp = (si == 0) ? cort : (si == 1) ? subc : vent;
      rp += base;
#pragma unroll
      for (int t = 0; t < 4; ++t) {
        int c = t * 64 + (tid >> 3) * 2;    // even channel
        float4 fa = *(const float4*)(rp + (size_t)c * 4096 + p4);
        float4 fb = *(const float4*)(rp + (size_t)(c + 1) * 4096 + p4);
#pragma unroll
        for (int k = 0; k < 4; ++k) {
          int m = si * 32 + p4 + k;
          float va = (k == 0) ? fa.x : (k == 1) ? fa.y : (k == 2) ? fa.z : fa.w;
          float vb = (k == 0) ? fb.x : (k == 1) ? fb.y : (k == 2) ? fb.z : fb.w;
          unsigned off = ((unsigned)(m * 512 + c * 2)) ^ ((unsigned)(m & 31) << 4);
          *(unsigned*)(smem + XOFF + off) = (unsigned)f2b(va) | ((unsigned)f2b(vb) << 16);
        }
      }
    }
  }

  f32x4 accY[6][4] = {};   // persistent out_proj accumulators: wave owns 64 N-cols, all 96 M-rows

  __syncthreads();   // B1

  const int ph = wv & 1;   // pixel half (16 pixels)
  const int hg = wv >> 1;  // head group (4 heads)
  const float SC = 0.17677669529663687f;  // 1/sqrt(32)

  for (int hh = 0; hh < 4; ++hh) {
    const int h = hg * 4 + hh;
    // hoisted bias loads (hide under QKV)
    float bq0 = b_in[h * 32 + l15],       bq1 = b_in[h * 32 + 16 + l15];
    float bk0 = b_in[256 + h * 32 + l15], bk1 = b_in[256 + h * 32 + 16 + l15];
    float bv0 = b_in[512 + h * 32 + l15], bv1 = b_in[512 + h * 32 + 16 + l15];

    // ---------- QKV GEMM for head h, this wave's 16 pixels ----------
    f32x4 acc[3][6] = {};   // [token s][0,1=q 2,3=k 4,5=v]
#pragma unroll
    for (int ks = 0; ks < 8; ++ks) {
      const int k0 = ks * 32;
      bf16x8 af[3], bfr[6];
#pragma unroll
      for (int s = 0; s < 3; ++s) {
        int m = s * 32 + ph * 16 + l15;
        unsigned off = ((unsigned)(m * 512 + (k0 + l4 * 8) * 2)) ^ ((unsigned)(m & 31) << 4);
        af[s] = *(const bf16x8*)(smem + XOFF + off);
      }
#pragma unroll
      for (int j = 0; j < 6; ++j) {
        int jb = (j >> 1) * 256 + h * 32 + (j & 1) * 16 + l15;
        bfr[j] = *(const bf16x8*)(w_in + (size_t)jb * 256 + k0 + l4 * 8);
      }
#pragma unroll
      for (int s = 0; s < 3; ++s)
#pragma unroll
        for (int j = 0; j < 6; ++j)
          acc[s][j] = __builtin_amdgcn_mfma_f32_16x16x32_bf16(af[s], bfr[j], acc[s][j], 0, 0, 0);
    }
#pragma unroll
    for (int s = 0; s < 3; ++s)
#pragma unroll
      for (int r = 0; r < 4; ++r) {
        acc[s][0][r] += bq0; acc[s][1][r] += bq1;
        acc[s][2][r] += bk0; acc[s][3][r] += bk1;
        acc[s][4][r] += bv0; acc[s][5][r] += bv1;
      }

    // ---------- in-register attention; lane holds d=jq*16+l15, pixel p=ph*16+l4*4+r ----------
    char* ob = OB(hg, hh & 1);
#pragma unroll
    for (int si = 0; si < 3; ++si) {
      float pp[3][4];
#pragma unroll
      for (int ti = 0; ti < 3; ++ti)
#pragma unroll
        for (int r = 0; r < 4; ++r)
          pp[ti][r] = acc[si][0][r] * acc[ti][2][r] + acc[si][1][r] * acc[ti][3][r];
#pragma unroll
      for (int mask = 1; mask <= 8; mask <<= 1)
#pragma unroll
        for (int ti = 0; ti < 3; ++ti)
#pragma unroll
          for (int r = 0; r < 4; ++r)
            pp[ti][r] += __shfl_xor(pp[ti][r], mask);
#pragma unroll
      for (int r = 0; r < 4; ++r) {
        float s0 = pp[0][r] * SC, s1 = pp[1][r] * SC, s2 = pp[2][r] * SC;
        float mx = fmaxf(fmaxf(s0, s1), s2);
        float e0 = __expf(s0 - mx), e1 = __expf(s1 - mx), e2 = __expf(s2 - mx);
        float inv = 1.f / (e0 + e1 + e2);
        e0 *= inv; e1 *= inv; e2 *= inv;
        int m = si * 32 + ph * 16 + l4 * 4 + r;
#pragma unroll
        for (int jq = 0; jq < 2; ++jq) {
          float ov = e0 * acc[0][4 + jq][r] + e1 * acc[1][4 + jq][r] + e2 * acc[2][4 + jq][r];
          *(__bf16*)(ob + m * 80 + (jq * 16 + l15) * 2) = (__bf16)ov;
        }
      }
    }
    __syncthreads();   // single barrier/iter: writes(buf b) before reads(buf b); alternation guards reuse

    // ---------- out_proj partial: K-slices of heads hh and 4+hh ----------
    {
      const int b = hh & 1;
      bf16x8 afA[6], afB[6], bfA[4], bfB[4];
#pragma unroll
      for (int i = 0; i < 6; ++i) {
        int ro = (i * 16 + l15) * 80 + l4 * 16;
        afA[i] = *(const bf16x8*)(OB(0, b) + ro);
        afB[i] = *(const bf16x8*)(OB(1, b) + ro);
      }
#pragma unroll
      for (int j = 0; j < 4; ++j) {
        int jr = wv * 64 + j * 16 + l15;
        bfA[j] = *(const bf16x8*)(w_out + (size_t)jr * 256 + hh * 32 + l4 * 8);
        bfB[j] = *(const bf16x8*)(w_out + (size_t)jr * 256 + (4 + hh) * 32 + l4 * 8);
      }
#pragma unroll
      for (int i = 0; i < 6; ++i)
#pragma unroll
        for (int j = 0; j < 4; ++j) {
          accY[i][j] = __builtin_amdgcn_mfma_f32_16x16x32_bf16(afA[i], bfA[j], accY[i][j], 0, 0, 0);
          accY[i][j] = __builtin_amdgcn_mfma_f32_16x16x32_bf16(afB[i], bfB[j], accY[i][j], 0, 0, 0);
        }
    }
  }  // head loop
  __syncthreads();   // all out_proj o-reads done; o-region reusable for LN partials

  // ---------- bias + residual + LayerNorm partials ----------
  float bo[4], gg[4], bb2[4];
#pragma unroll
  for (int j = 0; j < 4; ++j) {
    int jc = wv * 64 + j * 16 + l15;
    bo[j] = b_out[jc];
    gg[j] = gamma[jc];
    bb2[j] = beta[jc];
  }
#pragma unroll
  for (int i = 0; i < 6; ++i)
#pragma unroll
    for (int r = 0; r < 4; ++r) {
      int m = i * 16 + l4 * 4 + r;
      float s1 = 0.f, s2 = 0.f;
#pragma unroll
      for (int j = 0; j < 4; ++j) {
        int jc = wv * 64 + j * 16 + l15;
        unsigned xo = ((unsigned)(m * 512 + jc * 2)) ^ ((unsigned)(m & 31) << 4);
        float xv = (float)(*(const __bf16*)(smem + XOFF + xo));
        float v = accY[i][j][r] + bo[j] + xv;
        accY[i][j][r] = v;
        s1 += v;
        s2 += v * v;
      }
      s1 += __shfl_xor(s1, 1); s2 += __shfl_xor(s2, 1);
      s1 += __shfl_xor(s1, 2); s2 += __shfl_xor(s2, 2);
      s1 += __shfl_xor(s1, 4); s2 += __shfl_xor(s2, 4);
      s1 += __shfl_xor(s1, 8); s2 += __shfl_xor(s2, 8);
      if (l15 == 0) {
        *(float*)(smem + PSOFF + (m * 4 + wv) * 4) = s1;
        *(float*)(smem + PQOFF + (m * 4 + wv) * 4) = s2;
      }
    }
  __syncthreads();
  if (tid < 96) {
    float s = 0.f, q = 0.f;
#pragma unroll
    for (int j = 0; j < 4; ++j) {
      s += *(const float*)(smem + PSOFF + (tid * 4 + j) * 4);
      q += *(const float*)(smem + PQOFF + (tid * 4 + j) * 4);
    }
    float mu  = s * (1.f / 256.f);
    float var = q * (1.f / 256.f) - mu * mu;
    *(float*)(smem + MUOFF + tid * 4) = mu;
    *(float*)(smem + RSOFF + tid * 4) = rsqrtf(var + 1e-5f);
  }
  __syncthreads();
  // rescale + write y bf16 into [32][768] swz (aliases x; all x reads done)
#pragma unroll
  for (int i = 0; i < 6; ++i)
#pragma unroll
    for (int r = 0; r < 4; ++r) {
      int m = i * 16 + l4 * 4 + r;
      float mu = *(const float*)(smem + MUOFF + m * 4);
      float rs = *(const float*)(smem + RSOFF + m * 4);
      int s = m >> 5, p = m & 31;
#pragma unroll
      for (int j = 0; j < 4; ++j) {
        int jc = wv * 64 + j * 16 + l15;
        float yv = (accY[i][j][r] - mu) * rs * gg[j] + bb2[j];
        int kk = s * 256 + jc;
        unsigned off = ((unsigned)(p * 1536 + kk * 2)) ^ ((unsigned)(p & 31) << 4);
        *(__bf16*)(smem + XOFF + off) = (__bf16)yv;
      }
    }
  __syncthreads();

  // ---------- 1x1 conv: M=cout(256, wave owns 64), N=pixel(32), K=768 ----------
  {
    f32x4 accC[4][2] = {};
#pragma unroll 4
    for (int ks = 0; ks < 24; ++ks) {
      const int k0 = ks * 32;
      bf16x8 af[4], bfr2[2];
#pragma unroll
      for (int i = 0; i < 4; ++i) {
        int co = wv * 64 + i * 16 + l15;
        af[i] = *(const bf16x8*)(w_conv + (size_t)co * 768 + k0 + l4 * 8);
      }
#pragma unroll
      for (int j = 0; j < 2; ++j) {
        int p = j * 16 + l15;
        unsigned off = ((unsigned)(p * 1536 + (k0 + l4 * 8) * 2)) ^ ((unsigned)(p & 31) << 4);
        bfr2[j] = *(const bf16x8*)(smem + XOFF + off);
      }
#pragma unroll
      for (int i = 0; i < 4; ++i)
#pragma unroll
        for (int j = 0; j < 2; ++j)
          accC[i][j] = __builtin_amdgcn_mfma_f32_16x16x32_bf16(af[i], bfr2[j], accC[i][j], 0, 0, 0);
    }
#pragma unroll
    for (int i = 0; i < 4; ++i)
#pragma unroll
      for (int r = 0; r < 4; ++r) {
        int co = wv * 64 + i * 16 + l4 * 4 + r;
        float cb = b_conv[co];
#pragma unroll
        for (int j = 0; j < 2; ++j)
          out[((size_t)img * 256 + co) * 4096 + pixbase + j * 16 + l15] = accC[i][j][r] + cb;
      }
  }
}

extern "C" void kernel_launch(void* const* d_in, const int* in_sizes, int n_in,
                              void* d_out, int out_size, void* d_ws, size_t ws_size,
                              hipStream_t stream) {
  (void)in_sizes; (void)n_in; (void)out_size; (void)ws_size;
  const float* cort    = (const float*)d_in[0];
  const float* subc    = (const float*)d_in[1];
  const float* vent    = (const float*)d_in[2];
  const float* w_in_f  = (const float*)d_in[3];
  const float* b_in    = (const float*)d_in[4];
  const float* w_out_f = (const float*)d_in[5];
  const float* b_out   = (const float*)d_in[6];
  const float* gamma   = (const float*)d_in[7];
  const float* beta    = (const float*)d_in[8];
  const float* w_conv_f= (const float*)d_in[9];
  const float* b_conv  = (const float*)d_in[10];

  __bf16* ws = (__bf16*)d_ws;   // 458752 bf16 = 917504 B
  convert_weights<<<448, 256, 0, stream>>>(w_in_f, w_out_f, w_conv_f, ws);
  crf_fused<<<1024, 256, SMEM_BYTES, stream>>>(
      cort, subc, vent,
      ws,            b_in,
      ws + 196608,   b_out,
      gamma,         beta,
      ws + 262144,   b_conv,
      (float*)d_out);
}